// Round 10
// baseline (1848.308 us; speedup 1.0000x reference)
//
#include <hip/hip_runtime.h>
#include <cstdint>
#include <cmath>

#define H 64
#define NFEAT 32
#define NNHID 128
#define MSG_EDGES 64   // 4 waves * 16 edges

typedef __attribute__((ext_vector_type(8))) short bf16x8;
typedef __attribute__((ext_vector_type(4))) float f32x4;

static __device__ __forceinline__ float sigmoidf_(float x) { return 1.f / (1.f + expf(-x)); }

static __device__ __forceinline__ unsigned bf16_rne_bits(float v) {
  unsigned u = __float_as_uint(v);
  return (u + 0x7fffu + ((u >> 16) & 1u)) >> 16;
}

// ---------------- generic fill ----------------
__global__ void fill_u32_k(uint32_t* __restrict__ p, uint32_t v, long long n) {
  long long i = (long long)blockIdx.x * blockDim.x + threadIdx.x;
  long long stride = (long long)gridDim.x * blockDim.x;
  for (; i < n; i += stride) p[i] = v;
}

// ---------------- degree ----------------
__global__ void count_deg_k(const int* __restrict__ dst, float* __restrict__ deg, int E) {
  int i = blockIdx.x * 256 + threadIdx.x;
  if (i < E) atomicAdd(&deg[dst[i]], 1.f);
}
__global__ void inv_deg_k(float* __restrict__ deg, int n) {
  int i = blockIdx.x * 256 + threadIdx.x;
  if (i < n) deg[i] = 1.f / fmaxf(deg[i], 1.f);
}

// ---------------- graph ranges via boundary detection (batch sorted) ----------------
__global__ void bounds_k(const int* __restrict__ batch, int* __restrict__ gs,
                         int* __restrict__ ge, int n) {
  int i = blockIdx.x * 256 + threadIdx.x;
  if (i >= n) return;
  int b = batch[i];
  if (i == 0) {
    gs[b] = 0;
  } else {
    int pb = batch[i - 1];
    if (pb != b) { gs[b] = i; ge[pb] = i; }
  }
  if (i == n - 1) ge[b] = n;
}

// ---------------- lin0 ----------------
__global__ __launch_bounds__(256) void lin0_k(const float* __restrict__ x,
    const float* __restrict__ w, const float* __restrict__ b,
    float* __restrict__ out, int n) {
  __shared__ float xr[4][NFEAT];
  int t = threadIdx.x;
  int nodeblk = blockIdx.x * 4;
  if (t < 4 * NFEAT) {
    int nn = nodeblk + t / NFEAT;
    xr[t / NFEAT][t % NFEAT] = (nn < n) ? x[(size_t)nn * NFEAT + (t % NFEAT)] : 0.f;
  }
  __syncthreads();
  int node = nodeblk + t / H;
  int c = t % H;
  if (node >= n) return;
  float acc = b[c];
  #pragma unroll
  for (int j = 0; j < NFEAT; ++j) acc += xr[t / H][j] * w[j * H + c];
  out[(size_t)node * H + c] = fmaxf(acc, 0.f);
}

// ------------- edge MLP layer1 + direct split-bf16 A-fragment pack -------------
__global__ __launch_bounds__(128) void edge_mlp1_pack_k(const float* __restrict__ ea,
    const float* __restrict__ w1, const float* __restrict__ b1,
    short* __restrict__ hi, short* __restrict__ lo, int E) {
  __shared__ float ar[64][H];        // [edge][j]
  __shared__ float ut[NNHID][65];    // [k][e] padded
  int t = threadIdx.x;
  int e0 = blockIdx.x * 64;
  #pragma unroll
  for (int p = 0; p < 32; ++p) {
    int idx = p * 128 + t;
    int e = idx >> 6, j = idx & 63;
    ar[e][j] = (e0 + e < E) ? ea[(size_t)(e0 + e) * H + j] : 0.f;
  }
  __syncthreads();
  float bb = b1[t];
  for (int et = 0; et < 64; et += 16) {
    float acc[16];
    #pragma unroll
    for (int q = 0; q < 16; ++q) acc[q] = bb;
    #pragma unroll
    for (int j = 0; j < H; ++j) {
      float wv = w1[j * NNHID + t];
      #pragma unroll
      for (int q = 0; q < 16; ++q) acc[q] += ar[et + q][j] * wv;
    }
    #pragma unroll
    for (int q = 0; q < 16; ++q) ut[t][et + q] = fmaxf(acc[q], 0.f);
  }
  __syncthreads();
  // pack 16 local frags (4 etiles x 4 kt), 2 waves
  int wv = t >> 6, ln = t & 63;
  int erow = ln & 15;
  int k0b = (ln >> 4) * 8;
  for (int fi = wv; fi < 16; fi += 2) {
    int et = fi >> 2, kt = fi & 3;
    int k0 = kt * 32 + k0b;
    bool valid = (e0 + et * 16 + erow) < E;
    bf16x8 hv, lv;
    #pragma unroll
    for (int b = 0; b < 8; ++b) {
      float v = valid ? ut[k0 + b][et * 16 + erow] : 0.f;
      unsigned hb = bf16_rne_bits(v);
      float hf = __uint_as_float(hb << 16);
      unsigned lb = bf16_rne_bits(v - hf);
      hv[b] = (short)hb;
      lv[b] = (short)lb;
    }
    size_t frag = ((size_t)(e0 >> 4) + et) * 4 + kt;
    size_t off = frag * 512 + ln * 8;
    *(bf16x8*)(hi + off) = hv;
    *(bf16x8*)(lo + off) = lv;
  }
}

// ------- pack w2[128][4096] fp32 -> split-bf16 B fragments -------
__global__ __launch_bounds__(256) void pack_w2_k(const float* __restrict__ w2,
    short* __restrict__ hi, short* __restrict__ lo) {
  int g = blockIdx.x * 256 + threadIdx.x;
  int lane = g & 63, frag = g >> 6;
  if (frag >= 1024) return;
  int ntile = frag >> 2, kt = frag & 3;
  int n = ntile * 16 + (lane & 15);
  int k0 = kt * 32 + (lane >> 4) * 8;
  bf16x8 hv, lv;
  #pragma unroll
  for (int b = 0; b < 8; ++b) {
    float v = w2[(size_t)(k0 + b) * 4096 + n];
    unsigned hb = bf16_rne_bits(v);
    float hf = __uint_as_float(hb << 16);
    unsigned lb = bf16_rne_bits(v - hf);
    hv[b] = (short)hb;
    lv[b] = (short)lb;
  }
  size_t off = (size_t)frag * 512 + lane * 8;
  *(bf16x8*)(hi + off) = hv;
  *(bf16x8*)(lo + off) = lv;
}

// ------- fused W-GEMM (split-bf16 MFMA) + einsum + scatter-mean -------
// 4 waves/WG, 16 edges/wave, 64 edges/WG -> grid 1250 (occupancy!).
// Waves kept i-synchronized with one barrier per i-step so their identical
// B-fragment reads hit L1 (per-i working set = 32 KB = L1 size).
__global__ __launch_bounds__(256, 5) void fused_msg_k(
    const short* __restrict__ upk_hi, const short* __restrict__ upk_lo,
    const short* __restrict__ wpk_hi, const short* __restrict__ wpk_lo,
    const float* __restrict__ out, const int* __restrict__ src,
    const int* __restrict__ dst, const float* __restrict__ inv_deg,
    const float* __restrict__ b2, float* __restrict__ agg, int E) {
  __shared__ float s_lds[MSG_EDGES][H + 1];   // 16.64 KB
  int t = threadIdx.x;
  int e0 = blockIdx.x * MSG_EDGES;
  int wave = t >> 6, lane = t & 63;

  // stage s = out[src[e]]
  for (int row = wave; row < MSG_EDGES; row += 4) {
    int e = e0 + row;
    int ee = e < E ? e : E - 1;
    int sn = src[ee];
    s_lds[row][lane] = out[(size_t)sn * H + lane];
  }
  __syncthreads();

  int lrow4 = (lane >> 4) * 4;
  int lcol = lane & 15;
  int ebase = e0 + wave * 16;
  int srow = wave * 16;
  int etmax = (E - 1) >> 4;
  int et = ebase >> 4;
  if (et > etmax) et = etmax;
  size_t abase = (size_t)et * 4 * 512 + lane * 8;

  // A fragments: 4 ktiles, hi+lo = 8 frags = 32 VGPR, resident whole kernel
  bf16x8 ah[4], al[4];
  #pragma unroll
  for (int kt = 0; kt < 4; ++kt) {
    ah[kt] = *(const bf16x8*)(upk_hi + abase + (size_t)kt * 512);
    al[kt] = *(const bf16x8*)(upk_lo + abase + (size_t)kt * 512);
  }

  f32x4 msg[4];
  #pragma unroll
  for (int oc = 0; oc < 4; ++oc) msg[oc] = (f32x4){0.f, 0.f, 0.f, 0.f};

  const short* wh = wpk_hi + lane * 8;
  const short* wl = wpk_lo + lane * 8;

  #pragma unroll 1
  for (int i = 0; i < H; ++i) {
    float sv[4];
    #pragma unroll
    for (int r = 0; r < 4; ++r) sv[r] = s_lds[srow + lrow4 + r][i];
    #pragma unroll
    for (int oc = 0; oc < 4; ++oc) {
      size_t f0 = (size_t)((i * 4 + oc) * 4) * 512;
      bf16x8 bh0 = *(const bf16x8*)(wh + f0);
      bf16x8 bh1 = *(const bf16x8*)(wh + f0 + 512);
      bf16x8 bh2 = *(const bf16x8*)(wh + f0 + 1024);
      bf16x8 bh3 = *(const bf16x8*)(wh + f0 + 1536);
      bf16x8 bl0 = *(const bf16x8*)(wl + f0);
      bf16x8 bl1 = *(const bf16x8*)(wl + f0 + 512);
      bf16x8 bl2 = *(const bf16x8*)(wl + f0 + 1024);
      bf16x8 bl3 = *(const bf16x8*)(wl + f0 + 1536);
      float b2v = b2[i * 64 + oc * 16 + lcol];
      f32x4 acc = (f32x4){0.f, 0.f, 0.f, 0.f};
      acc = __builtin_amdgcn_mfma_f32_16x16x32_bf16(ah[0], bh0, acc, 0, 0, 0);
      acc = __builtin_amdgcn_mfma_f32_16x16x32_bf16(ah[0], bl0, acc, 0, 0, 0);
      acc = __builtin_amdgcn_mfma_f32_16x16x32_bf16(al[0], bh0, acc, 0, 0, 0);
      acc = __builtin_amdgcn_mfma_f32_16x16x32_bf16(ah[1], bh1, acc, 0, 0, 0);
      acc = __builtin_amdgcn_mfma_f32_16x16x32_bf16(ah[1], bl1, acc, 0, 0, 0);
      acc = __builtin_amdgcn_mfma_f32_16x16x32_bf16(al[1], bh1, acc, 0, 0, 0);
      acc = __builtin_amdgcn_mfma_f32_16x16x32_bf16(ah[2], bh2, acc, 0, 0, 0);
      acc = __builtin_amdgcn_mfma_f32_16x16x32_bf16(ah[2], bl2, acc, 0, 0, 0);
      acc = __builtin_amdgcn_mfma_f32_16x16x32_bf16(al[2], bh2, acc, 0, 0, 0);
      acc = __builtin_amdgcn_mfma_f32_16x16x32_bf16(ah[3], bh3, acc, 0, 0, 0);
      acc = __builtin_amdgcn_mfma_f32_16x16x32_bf16(ah[3], bl3, acc, 0, 0, 0);
      acc = __builtin_amdgcn_mfma_f32_16x16x32_bf16(al[3], bh3, acc, 0, 0, 0);
      #pragma unroll
      for (int r = 0; r < 4; ++r)
        msg[oc][r] += sv[r] * (acc[r] + b2v);
    }
    __syncthreads();   // keep 4 waves i-synchronized -> B reads L1-shared
  }

  // scatter-mean writeback
  #pragma unroll
  for (int r = 0; r < 4; ++r) {
    int e = ebase + lrow4 + r;
    if (e < E) {
      int dn = dst[e];
      float idg = inv_deg[dn];
      #pragma unroll
      for (int oc = 0; oc < 4; ++oc) {
        atomicAdd(&agg[(size_t)dn * H + oc * 16 + lcol], msg[oc][r] * idg);
      }
    }
  }
}

// ------- fused conv + GRU (+ agg re-zero for next iteration) -------
__global__ __launch_bounds__(192) void convgru_k(float* __restrict__ agg,
    const float* __restrict__ h, const float* __restrict__ root,
    const float* __restrict__ cbias,
    const float* __restrict__ wih, const float* __restrict__ whh,
    const float* __restrict__ bih, const float* __restrict__ bhh,
    float* __restrict__ hnew, int n) {
  __shared__ float h_lds[16][H], m_lds[16][H];
  __shared__ float gib[16][192], ghb[16][192];
  int t = threadIdx.x;
  int n0 = blockIdx.x * 16;
  for (int p = 0; p < 6; ++p) {
    int idx = p * 192 + t;
    if (idx < 16 * H) {
      int q = idx >> 6, c = idx & 63;
      int nn = n0 + q;
      h_lds[q][c] = (nn < n) ? h[(size_t)nn * H + c] : 0.f;
    }
  }
  __syncthreads();
  for (int p = 0; p < 6; ++p) {
    int idx = p * 192 + t;
    if (idx < 16 * H) {
      int q = idx >> 6, c = idx & 63;
      int nn = n0 + q;
      float acc = cbias[c];
      if (nn < n) acc += agg[(size_t)nn * H + c];
      #pragma unroll
      for (int j = 0; j < H; ++j) acc += h_lds[q][j] * root[j * H + c];
      m_lds[q][c] = fmaxf(acc, 0.f);
      if (nn < n) agg[(size_t)nn * H + c] = 0.f;
    }
  }
  __syncthreads();
  float gi[16], gh[16];
  float bi = bih[t], bh = bhh[t];
  #pragma unroll
  for (int q = 0; q < 16; ++q) { gi[q] = bi; gh[q] = bh; }
  for (int j = 0; j < H; ++j) {
    float wi = wih[j * 192 + t];
    float wh = whh[j * 192 + t];
    #pragma unroll
    for (int q = 0; q < 16; ++q) {
      gi[q] += m_lds[q][j] * wi;
      gh[q] += h_lds[q][j] * wh;
    }
  }
  #pragma unroll
  for (int q = 0; q < 16; ++q) { gib[q][t] = gi[q]; ghb[q][t] = gh[q]; }
  __syncthreads();
  for (int p = 0; p < 6; ++p) {
    int idx = p * 192 + t;
    if (idx < 16 * H) {
      int q = idx >> 6, c = idx & 63;
      int nn = n0 + q;
      if (nn < n) {
        float r = sigmoidf_(gib[q][c] + ghb[q][c]);
        float z = sigmoidf_(gib[q][64 + c] + ghb[q][64 + c]);
        float ng = tanhf(gib[q][128 + c] + r * ghb[q][128 + c]);
        hnew[(size_t)nn * H + c] = (1.f - z) * ng + z * h_lds[q][c];
      }
    }
  }
}

// ------- fused Set2Set (3 steps of LSTM + attention) + final MLP -------
__global__ __launch_bounds__(256) void set2set_k(const float* __restrict__ out,
    const int* __restrict__ gstart, const int* __restrict__ gend,
    const float* __restrict__ wih, const float* __restrict__ whh,
    const float* __restrict__ bih, const float* __restrict__ bhh,
    const float* __restrict__ w1, const float* __restrict__ b1,
    const float* __restrict__ w2, const float* __restrict__ b2o,
    float* __restrict__ en, float* __restrict__ outp) {
  int b = blockIdx.x;
  int t = threadIdx.x;
  __shared__ float q_star[2 * H];
  __shared__ float hh[H], cc[H], q[H];
  __shared__ float gate[256];
  __shared__ float red[256];
  if (t < 2 * H) q_star[t] = 0.f;
  if (t >= 128 && t < 192) { hh[t - 128] = 0.f; cc[t - 128] = 0.f; }
  int s = gstart[b], epos = gend[b];
  if (s > epos) { s = 0; epos = 0; }
  __syncthreads();
  for (int step = 0; step < 3; ++step) {
    float acc = bih[t] + bhh[t];
    #pragma unroll 4
    for (int j = 0; j < 2 * H; ++j) acc += q_star[j] * wih[j * 256 + t];
    #pragma unroll 4
    for (int j = 0; j < H; ++j) acc += hh[j] * whh[j * 256 + t];
    gate[t] = acc;
    __syncthreads();
    if (t < H) {
      float ig = sigmoidf_(gate[t]);
      float fg = sigmoidf_(gate[64 + t]);
      float gg = tanhf(gate[128 + t]);
      float og = sigmoidf_(gate[192 + t]);
      float c2 = fg * cc[t] + ig * gg;
      cc[t] = c2;
      float h2 = og * tanhf(c2);
      hh[t] = h2;
      q[t] = h2;
    }
    __syncthreads();
    float lmax = -INFINITY;
    for (int nn = s + t; nn < epos; nn += 256) {
      float d = 0.f;
      const float* orow = &out[(size_t)nn * H];
      #pragma unroll
      for (int j = 0; j < H; ++j) d += orow[j] * q[j];
      en[nn] = d;
      lmax = fmaxf(lmax, d);
    }
    red[t] = lmax;
    __syncthreads();
    for (int st = 128; st > 0; st >>= 1) {
      if (t < st) red[t] = fmaxf(red[t], red[t + st]);
      __syncthreads();
    }
    float mx = red[0];
    __syncthreads();
    float lsum = 0.f;
    for (int nn = s + t; nn < epos; nn += 256) {
      float e_ = expf(en[nn] - mx);
      en[nn] = e_;
      lsum += e_;
    }
    red[t] = lsum;
    __syncthreads();
    for (int st = 128; st > 0; st >>= 1) {
      if (t < st) red[t] += red[t + st];
      __syncthreads();
    }
    float inv = 1.f / (red[0] + 1e-16f);
    __syncthreads();
    int hch = t & 63, sub = t >> 6;
    float racc = 0.f;
    for (int nn = s + sub; nn < epos; nn += 4) {
      racc += en[nn] * out[(size_t)nn * H + hch];
    }
    red[t] = racc;
    __syncthreads();
    if (t < H) {
      float r = (red[t] + red[64 + t] + red[128 + t] + red[192 + t]) * inv;
      q_star[t] = q[t];
      q_star[H + t] = r;
    }
    __syncthreads();
  }
  if (t < H) {
    float acc = b1[t];
    #pragma unroll 4
    for (int j = 0; j < 2 * H; ++j) acc += q_star[j] * w1[j * H + t];
    acc = fmaxf(acc, 0.f);
    red[t] = acc * w2[t];
  }
  __syncthreads();
  if (t < 64) {
    float v = red[t];
    #pragma unroll
    for (int off = 32; off > 0; off >>= 1) v += __shfl_down(v, off, 64);
    if (t == 0) outp[b] = v + b2o[0];
  }
}

extern "C" void kernel_launch(void* const* d_in, const int* in_sizes, int n_in,
                              void* d_out, int out_size, void* d_ws, size_t ws_size,
                              hipStream_t stream) {
  const float* x         = (const float*)d_in[0];
  const int*   edge_idx  = (const int*)d_in[1];
  const int*   batch     = (const int*)d_in[2];
  const float* edge_attr = (const float*)d_in[3];
  const float* lin0_w = (const float*)d_in[4];
  const float* lin0_b = (const float*)d_in[5];
  const float* nn_w1  = (const float*)d_in[6];
  const float* nn_b1  = (const float*)d_in[7];
  const float* nn_w2  = (const float*)d_in[8];
  const float* nn_b2  = (const float*)d_in[9];
  const float* conv_root = (const float*)d_in[10];
  const float* conv_bias = (const float*)d_in[11];
  const float* gru_wih = (const float*)d_in[12];
  const float* gru_whh = (const float*)d_in[13];
  const float* gru_bih = (const float*)d_in[14];
  const float* gru_bhh = (const float*)d_in[15];
  const float* lstm_wih = (const float*)d_in[16];
  const float* lstm_whh = (const float*)d_in[17];
  const float* lstm_bih = (const float*)d_in[18];
  const float* lstm_bhh = (const float*)d_in[19];
  const float* lin1_w = (const float*)d_in[20];
  const float* lin1_b = (const float*)d_in[21];
  const float* lin2_w = (const float*)d_in[22];
  const float* lin2_b = (const float*)d_in[23];

  int N = in_sizes[2];
  int E = in_sizes[1] / 2;
  int B = out_size;
  const int* src = edge_idx;
  const int* dst = edge_idx + E;

  char* p = (char*)d_ws;
  auto carve = [&](size_t bytes) -> void* {
    void* r = (void*)p;
    p += (bytes + 255) & ~(size_t)255;
    return r;
  };
  int etiles = (E + 15) / 16;
  int nfrag_u = etiles * 4;
  float* bufA   = (float*)carve((size_t)N * H * 4);
  float* bufB   = (float*)carve((size_t)N * H * 4);
  short* upk_hi = (short*)carve((size_t)nfrag_u * 512 * 2);
  short* upk_lo = (short*)carve((size_t)nfrag_u * 512 * 2);
  short* wpk_hi = (short*)carve((size_t)1024 * 512 * 2);
  short* wpk_lo = (short*)carve((size_t)1024 * 512 * 2);
  float* enbuf  = (float*)carve((size_t)N * 4);
  // --- contiguous zero region: invdeg, agg, gstart, gend ---
  char* zero_begin = p;
  float* invdeg = (float*)carve((size_t)N * 4);
  float* agg    = (float*)carve((size_t)N * H * 4);
  int*   gstart = (int*)carve((size_t)B * 4);
  int*   gend   = (int*)carve((size_t)B * 4);
  long long zero_u32 = (long long)(p - zero_begin) / 4;

  dim3 b256(256);
  fill_u32_k<<<dim3(1024), b256, 0, stream>>>((uint32_t*)zero_begin, 0u, zero_u32);
  count_deg_k<<<dim3((E + 255) / 256), b256, 0, stream>>>(dst, invdeg, E);
  inv_deg_k<<<dim3((N + 255) / 256), b256, 0, stream>>>(invdeg, N);
  lin0_k<<<dim3((N + 3) / 4), b256, 0, stream>>>(x, lin0_w, lin0_b, bufA, N);
  bounds_k<<<dim3((N + 255) / 256), b256, 0, stream>>>(batch, gstart, gend, N);
  edge_mlp1_pack_k<<<dim3((E + 63) / 64), dim3(128), 0, stream>>>(
      edge_attr, nn_w1, nn_b1, upk_hi, upk_lo, E);
  pack_w2_k<<<dim3(256), b256, 0, stream>>>(nn_w2, wpk_hi, wpk_lo);

  float* cur = bufA;
  float* nxt = bufB;
  for (int it = 0; it < 3; ++it) {
    fused_msg_k<<<dim3((E + MSG_EDGES - 1) / MSG_EDGES), b256, 0, stream>>>(
        upk_hi, upk_lo, wpk_hi, wpk_lo, cur, src, dst, invdeg, nn_b2, agg, E);
    convgru_k<<<dim3((N + 15) / 16), dim3(192), 0, stream>>>(
        agg, cur, conv_root, conv_bias, gru_wih, gru_whh, gru_bih, gru_bhh, nxt, N);
    float* tmp = cur; cur = nxt; nxt = tmp;
  }
  set2set_k<<<dim3(B), b256, 0, stream>>>(cur, gstart, gend,
      lstm_wih, lstm_whh, lstm_bih, lstm_bhh, lin1_w, lin1_b, lin2_w, lin2_b,
      enbuf, (float*)d_out);
}

// Round 11
// 837.091 us; speedup vs baseline: 2.2080x; 2.2080x over previous
//
#include <hip/hip_runtime.h>
#include <cstdint>
#include <cmath>

#define H 64
#define NFEAT 32
#define NNHID 128
#define MSG_EDGES 192   // 4 waves * 48 edges

typedef __attribute__((ext_vector_type(8))) short bf16x8;
typedef __attribute__((ext_vector_type(4))) float f32x4;

static __device__ __forceinline__ float sigmoidf_(float x) { return 1.f / (1.f + expf(-x)); }

static __device__ __forceinline__ unsigned bf16_rne_bits(float v) {
  unsigned u = __float_as_uint(v);
  return (u + 0x7fffu + ((u >> 16) & 1u)) >> 16;
}

// ---------------- generic fill ----------------
__global__ void fill_u32_k(uint32_t* __restrict__ p, uint32_t v, long long n) {
  long long i = (long long)blockIdx.x * blockDim.x + threadIdx.x;
  long long stride = (long long)gridDim.x * blockDim.x;
  for (; i < n; i += stride) p[i] = v;
}

// ---------------- degree ----------------
__global__ void count_deg_k(const int* __restrict__ dst, float* __restrict__ deg, int E) {
  int i = blockIdx.x * 256 + threadIdx.x;
  if (i < E) atomicAdd(&deg[dst[i]], 1.f);
}
__global__ void inv_deg_k(float* __restrict__ deg, int n) {
  int i = blockIdx.x * 256 + threadIdx.x;
  if (i < n) deg[i] = 1.f / fmaxf(deg[i], 1.f);
}

// ---------------- graph ranges via boundary detection (batch sorted) ----------------
__global__ void bounds_k(const int* __restrict__ batch, int* __restrict__ gs,
                         int* __restrict__ ge, int n) {
  int i = blockIdx.x * 256 + threadIdx.x;
  if (i >= n) return;
  int b = batch[i];
  if (i == 0) {
    gs[b] = 0;
  } else {
    int pb = batch[i - 1];
    if (pb != b) { gs[b] = i; ge[pb] = i; }
  }
  if (i == n - 1) ge[b] = n;
}

// ---------------- lin0 ----------------
__global__ __launch_bounds__(256) void lin0_k(const float* __restrict__ x,
    const float* __restrict__ w, const float* __restrict__ b,
    float* __restrict__ out, int n) {
  __shared__ float xr[4][NFEAT];
  int t = threadIdx.x;
  int nodeblk = blockIdx.x * 4;
  if (t < 4 * NFEAT) {
    int nn = nodeblk + t / NFEAT;
    xr[t / NFEAT][t % NFEAT] = (nn < n) ? x[(size_t)nn * NFEAT + (t % NFEAT)] : 0.f;
  }
  __syncthreads();
  int node = nodeblk + t / H;
  int c = t % H;
  if (node >= n) return;
  float acc = b[c];
  #pragma unroll
  for (int j = 0; j < NFEAT; ++j) acc += xr[t / H][j] * w[j * H + c];
  out[(size_t)node * H + c] = fmaxf(acc, 0.f);
}

// ------------- edge MLP layer1 + direct split-bf16 A-fragment pack -------------
__global__ __launch_bounds__(128) void edge_mlp1_pack_k(const float* __restrict__ ea,
    const float* __restrict__ w1, const float* __restrict__ b1,
    short* __restrict__ hi, short* __restrict__ lo, int E) {
  __shared__ float ar[64][H];        // [edge][j]
  __shared__ float ut[NNHID][65];    // [k][e] padded
  int t = threadIdx.x;
  int e0 = blockIdx.x * 64;
  #pragma unroll
  for (int p = 0; p < 32; ++p) {
    int idx = p * 128 + t;
    int e = idx >> 6, j = idx & 63;
    ar[e][j] = (e0 + e < E) ? ea[(size_t)(e0 + e) * H + j] : 0.f;
  }
  __syncthreads();
  float bb = b1[t];
  for (int et = 0; et < 64; et += 16) {
    float acc[16];
    #pragma unroll
    for (int q = 0; q < 16; ++q) acc[q] = bb;
    #pragma unroll
    for (int j = 0; j < H; ++j) {
      float wv = w1[j * NNHID + t];
      #pragma unroll
      for (int q = 0; q < 16; ++q) acc[q] += ar[et + q][j] * wv;
    }
    #pragma unroll
    for (int q = 0; q < 16; ++q) ut[t][et + q] = fmaxf(acc[q], 0.f);
  }
  __syncthreads();
  // pack 16 local frags (4 etiles x 4 kt), 2 waves
  int wv = t >> 6, ln = t & 63;
  int erow = ln & 15;
  int k0b = (ln >> 4) * 8;
  for (int fi = wv; fi < 16; fi += 2) {
    int et = fi >> 2, kt = fi & 3;
    int k0 = kt * 32 + k0b;
    bool valid = (e0 + et * 16 + erow) < E;
    bf16x8 hv, lv;
    #pragma unroll
    for (int b = 0; b < 8; ++b) {
      float v = valid ? ut[k0 + b][et * 16 + erow] : 0.f;
      unsigned hb = bf16_rne_bits(v);
      float hf = __uint_as_float(hb << 16);
      unsigned lb = bf16_rne_bits(v - hf);
      hv[b] = (short)hb;
      lv[b] = (short)lb;
    }
    size_t frag = ((size_t)(e0 >> 4) + et) * 4 + kt;
    size_t off = frag * 512 + ln * 8;
    *(bf16x8*)(hi + off) = hv;
    *(bf16x8*)(lo + off) = lv;
  }
}

// ------- pack w2[128][4096] fp32 -> SINGLE bf16 B fragments (RNE) -------
__global__ __launch_bounds__(256) void pack_w2_k(const float* __restrict__ w2,
    short* __restrict__ hi) {
  int g = blockIdx.x * 256 + threadIdx.x;
  int lane = g & 63, frag = g >> 6;
  if (frag >= 1024) return;
  int ntile = frag >> 2, kt = frag & 3;
  int n = ntile * 16 + (lane & 15);
  int k0 = kt * 32 + (lane >> 4) * 8;
  bf16x8 hv;
  #pragma unroll
  for (int b = 0; b < 8; ++b) {
    float v = w2[(size_t)(k0 + b) * 4096 + n];
    hv[b] = (short)bf16_rne_bits(v);
  }
  size_t off = (size_t)frag * 512 + lane * 8;
  *(bf16x8*)(hi + off) = hv;
}

// ------- fused W-GEMM (split-A bf16 x single-B bf16 MFMA) + einsum + scatter-mean -------
// 4 waves/WG, 48 edges/wave (3 x 16-subtiles), 192 edges/WG.  (R5 structure, B traffic halved)
__global__ __launch_bounds__(256, 2) void fused_msg_k(
    const short* __restrict__ upk_hi, const short* __restrict__ upk_lo,
    const short* __restrict__ wpk_hi,
    const float* __restrict__ out, const int* __restrict__ src,
    const int* __restrict__ dst, const float* __restrict__ inv_deg,
    const float* __restrict__ b2, float* __restrict__ agg, int E) {
  __shared__ float s_lds[MSG_EDGES][H + 1];   // 49.9 KB
  int t = threadIdx.x;
  int e0 = blockIdx.x * MSG_EDGES;
  int wave = t >> 6, lane = t & 63;

  // stage s = out[src[e]]
  for (int rr = 0; rr < MSG_EDGES / 4; ++rr) {
    int row = wave + rr * 4;
    int e = e0 + row;
    int ee = e < E ? e : E - 1;
    int sn = src[ee];
    s_lds[row][lane] = out[(size_t)sn * H + lane];
  }
  __syncthreads();

  int lhi = lane >> 4;
  int lrow4 = lhi * 4;
  int lcol = lane & 15;
  int ebase = e0 + wave * 48;
  int srow = wave * 48;
  int etmax = (E - 1) >> 4;

  // A fragments: 3 subtiles x 4 ktiles, hi+lo (clamped etile; results discarded by e<E guard)
  bf16x8 a_hi[3][4], a_lo[3][4];
  #pragma unroll
  for (int ms = 0; ms < 3; ++ms) {
    int et = (ebase >> 4) + ms;
    if (et > etmax) et = etmax;
    size_t base = (size_t)et * 4 * 512 + lane * 8;
    #pragma unroll
    for (int kt = 0; kt < 4; ++kt) {
      a_hi[ms][kt] = *(const bf16x8*)(upk_hi + base + (size_t)kt * 512);
      a_lo[ms][kt] = *(const bf16x8*)(upk_lo + base + (size_t)kt * 512);
    }
  }

  f32x4 msg[3][4];
  #pragma unroll
  for (int ms = 0; ms < 3; ++ms)
    #pragma unroll
    for (int oc = 0; oc < 4; ++oc) msg[ms][oc] = (f32x4){0.f, 0.f, 0.f, 0.f};

  const short* wh = wpk_hi + lane * 8;

  for (int i = 0; i < H; ++i) {
    float sv[3][4];
    #pragma unroll
    for (int ms = 0; ms < 3; ++ms)
      #pragma unroll
      for (int r = 0; r < 4; ++r)
        sv[ms][r] = s_lds[srow + ms * 16 + lrow4 + r][i];
    #pragma unroll
    for (int oc = 0; oc < 4; ++oc) {
      int ntile = i * 4 + oc;
      float b2v = b2[i * 64 + oc * 16 + lcol];
      bf16x8 bh[4];
      #pragma unroll
      for (int kt = 0; kt < 4; ++kt) {
        size_t off = (size_t)(ntile * 4 + kt) * 512;
        bh[kt] = *(const bf16x8*)(wh + off);
      }
      #pragma unroll
      for (int ms = 0; ms < 3; ++ms) {
        f32x4 acc = (f32x4){0.f, 0.f, 0.f, 0.f};
        #pragma unroll
        for (int kt = 0; kt < 4; ++kt) {
          acc = __builtin_amdgcn_mfma_f32_16x16x32_bf16(a_hi[ms][kt], bh[kt], acc, 0, 0, 0);
          acc = __builtin_amdgcn_mfma_f32_16x16x32_bf16(a_lo[ms][kt], bh[kt], acc, 0, 0, 0);
        }
        #pragma unroll
        for (int r = 0; r < 4; ++r)
          msg[ms][oc][r] += sv[ms][r] * (acc[r] + b2v);
      }
    }
  }

  // scatter-mean writeback
  #pragma unroll
  for (int ms = 0; ms < 3; ++ms) {
    #pragma unroll
    for (int r = 0; r < 4; ++r) {
      int e = ebase + ms * 16 + lrow4 + r;
      if (e < E) {
        int dn = dst[e];
        float idg = inv_deg[dn];
        #pragma unroll
        for (int oc = 0; oc < 4; ++oc) {
          atomicAdd(&agg[(size_t)dn * H + oc * 16 + lcol], msg[ms][oc][r] * idg);
        }
      }
    }
  }
}

// ------- fused conv + GRU (+ agg re-zero for next iteration) -------
__global__ __launch_bounds__(192) void convgru_k(float* __restrict__ agg,
    const float* __restrict__ h, const float* __restrict__ root,
    const float* __restrict__ cbias,
    const float* __restrict__ wih, const float* __restrict__ whh,
    const float* __restrict__ bih, const float* __restrict__ bhh,
    float* __restrict__ hnew, int n) {
  __shared__ float h_lds[16][H], m_lds[16][H];
  __shared__ float gib[16][192], ghb[16][192];
  int t = threadIdx.x;
  int n0 = blockIdx.x * 16;
  for (int p = 0; p < 6; ++p) {
    int idx = p * 192 + t;
    if (idx < 16 * H) {
      int q = idx >> 6, c = idx & 63;
      int nn = n0 + q;
      h_lds[q][c] = (nn < n) ? h[(size_t)nn * H + c] : 0.f;
    }
  }
  __syncthreads();
  for (int p = 0; p < 6; ++p) {
    int idx = p * 192 + t;
    if (idx < 16 * H) {
      int q = idx >> 6, c = idx & 63;
      int nn = n0 + q;
      float acc = cbias[c];
      if (nn < n) acc += agg[(size_t)nn * H + c];
      #pragma unroll
      for (int j = 0; j < H; ++j) acc += h_lds[q][j] * root[j * H + c];
      m_lds[q][c] = fmaxf(acc, 0.f);
      if (nn < n) agg[(size_t)nn * H + c] = 0.f;
    }
  }
  __syncthreads();
  float gi[16], gh[16];
  float bi = bih[t], bh = bhh[t];
  #pragma unroll
  for (int q = 0; q < 16; ++q) { gi[q] = bi; gh[q] = bh; }
  for (int j = 0; j < H; ++j) {
    float wi = wih[j * 192 + t];
    float wh = whh[j * 192 + t];
    #pragma unroll
    for (int q = 0; q < 16; ++q) {
      gi[q] += m_lds[q][j] * wi;
      gh[q] += h_lds[q][j] * wh;
    }
  }
  #pragma unroll
  for (int q = 0; q < 16; ++q) { gib[q][t] = gi[q]; ghb[q][t] = gh[q]; }
  __syncthreads();
  for (int p = 0; p < 6; ++p) {
    int idx = p * 192 + t;
    if (idx < 16 * H) {
      int q = idx >> 6, c = idx & 63;
      int nn = n0 + q;
      if (nn < n) {
        float r = sigmoidf_(gib[q][c] + ghb[q][c]);
        float z = sigmoidf_(gib[q][64 + c] + ghb[q][64 + c]);
        float ng = tanhf(gib[q][128 + c] + r * ghb[q][128 + c]);
        hnew[(size_t)nn * H + c] = (1.f - z) * ng + z * h_lds[q][c];
      }
    }
  }
}

// ------- fused Set2Set (3 steps of LSTM + attention) + final MLP -------
__global__ __launch_bounds__(256) void set2set_k(const float* __restrict__ out,
    const int* __restrict__ gstart, const int* __restrict__ gend,
    const float* __restrict__ wih, const float* __restrict__ whh,
    const float* __restrict__ bih, const float* __restrict__ bhh,
    const float* __restrict__ w1, const float* __restrict__ b1,
    const float* __restrict__ w2, const float* __restrict__ b2o,
    float* __restrict__ en, float* __restrict__ outp) {
  int b = blockIdx.x;
  int t = threadIdx.x;
  __shared__ float q_star[2 * H];
  __shared__ float hh[H], cc[H], q[H];
  __shared__ float gate[256];
  __shared__ float red[256];
  if (t < 2 * H) q_star[t] = 0.f;
  if (t >= 128 && t < 192) { hh[t - 128] = 0.f; cc[t - 128] = 0.f; }
  int s = gstart[b], epos = gend[b];
  if (s > epos) { s = 0; epos = 0; }
  __syncthreads();
  for (int step = 0; step < 3; ++step) {
    float acc = bih[t] + bhh[t];
    #pragma unroll 4
    for (int j = 0; j < 2 * H; ++j) acc += q_star[j] * wih[j * 256 + t];
    #pragma unroll 4
    for (int j = 0; j < H; ++j) acc += hh[j] * whh[j * 256 + t];
    gate[t] = acc;
    __syncthreads();
    if (t < H) {
      float ig = sigmoidf_(gate[t]);
      float fg = sigmoidf_(gate[64 + t]);
      float gg = tanhf(gate[128 + t]);
      float og = sigmoidf_(gate[192 + t]);
      float c2 = fg * cc[t] + ig * gg;
      cc[t] = c2;
      float h2 = og * tanhf(c2);
      hh[t] = h2;
      q[t] = h2;
    }
    __syncthreads();
    float lmax = -INFINITY;
    for (int nn = s + t; nn < epos; nn += 256) {
      float d = 0.f;
      const float* orow = &out[(size_t)nn * H];
      #pragma unroll
      for (int j = 0; j < H; ++j) d += orow[j] * q[j];
      en[nn] = d;
      lmax = fmaxf(lmax, d);
    }
    red[t] = lmax;
    __syncthreads();
    for (int st = 128; st > 0; st >>= 1) {
      if (t < st) red[t] = fmaxf(red[t], red[t + st]);
      __syncthreads();
    }
    float mx = red[0];
    __syncthreads();
    float lsum = 0.f;
    for (int nn = s + t; nn < epos; nn += 256) {
      float e_ = expf(en[nn] - mx);
      en[nn] = e_;
      lsum += e_;
    }
    red[t] = lsum;
    __syncthreads();
    for (int st = 128; st > 0; st >>= 1) {
      if (t < st) red[t] += red[t + st];
      __syncthreads();
    }
    float inv = 1.f / (red[0] + 1e-16f);
    __syncthreads();
    int hch = t & 63, sub = t >> 6;
    float racc = 0.f;
    for (int nn = s + sub; nn < epos; nn += 4) {
      racc += en[nn] * out[(size_t)nn * H + hch];
    }
    red[t] = racc;
    __syncthreads();
    if (t < H) {
      float r = (red[t] + red[64 + t] + red[128 + t] + red[192 + t]) * inv;
      q_star[t] = q[t];
      q_star[H + t] = r;
    }
    __syncthreads();
  }
  if (t < H) {
    float acc = b1[t];
    #pragma unroll 4
    for (int j = 0; j < 2 * H; ++j) acc += q_star[j] * w1[j * H + t];
    acc = fmaxf(acc, 0.f);
    red[t] = acc * w2[t];
  }
  __syncthreads();
  if (t < 64) {
    float v = red[t];
    #pragma unroll
    for (int off = 32; off > 0; off >>= 1) v += __shfl_down(v, off, 64);
    if (t == 0) outp[b] = v + b2o[0];
  }
}

extern "C" void kernel_launch(void* const* d_in, const int* in_sizes, int n_in,
                              void* d_out, int out_size, void* d_ws, size_t ws_size,
                              hipStream_t stream) {
  const float* x         = (const float*)d_in[0];
  const int*   edge_idx  = (const int*)d_in[1];
  const int*   batch     = (const int*)d_in[2];
  const float* edge_attr = (const float*)d_in[3];
  const float* lin0_w = (const float*)d_in[4];
  const float* lin0_b = (const float*)d_in[5];
  const float* nn_w1  = (const float*)d_in[6];
  const float* nn_b1  = (const float*)d_in[7];
  const float* nn_w2  = (const float*)d_in[8];
  const float* nn_b2  = (const float*)d_in[9];
  const float* conv_root = (const float*)d_in[10];
  const float* conv_bias = (const float*)d_in[11];
  const float* gru_wih = (const float*)d_in[12];
  const float* gru_whh = (const float*)d_in[13];
  const float* gru_bih = (const float*)d_in[14];
  const float* gru_bhh = (const float*)d_in[15];
  const float* lstm_wih = (const float*)d_in[16];
  const float* lstm_whh = (const float*)d_in[17];
  const float* lstm_bih = (const float*)d_in[18];
  const float* lstm_bhh = (const float*)d_in[19];
  const float* lin1_w = (const float*)d_in[20];
  const float* lin1_b = (const float*)d_in[21];
  const float* lin2_w = (const float*)d_in[22];
  const float* lin2_b = (const float*)d_in[23];

  int N = in_sizes[2];
  int E = in_sizes[1] / 2;
  int B = out_size;
  const int* src = edge_idx;
  const int* dst = edge_idx + E;

  char* p = (char*)d_ws;
  auto carve = [&](size_t bytes) -> void* {
    void* r = (void*)p;
    p += (bytes + 255) & ~(size_t)255;
    return r;
  };
  int etiles = (E + 15) / 16;
  int nfrag_u = etiles * 4;
  float* bufA   = (float*)carve((size_t)N * H * 4);
  float* bufB   = (float*)carve((size_t)N * H * 4);
  short* upk_hi = (short*)carve((size_t)nfrag_u * 512 * 2);
  short* upk_lo = (short*)carve((size_t)nfrag_u * 512 * 2);
  short* wpk_hi = (short*)carve((size_t)1024 * 512 * 2);
  float* enbuf  = (float*)carve((size_t)N * 4);
  // --- contiguous zero region: invdeg, agg, gstart, gend ---
  char* zero_begin = p;
  float* invdeg = (float*)carve((size_t)N * 4);
  float* agg    = (float*)carve((size_t)N * H * 4);
  int*   gstart = (int*)carve((size_t)B * 4);
  int*   gend   = (int*)carve((size_t)B * 4);
  long long zero_u32 = (long long)(p - zero_begin) / 4;

  dim3 b256(256);
  fill_u32_k<<<dim3(1024), b256, 0, stream>>>((uint32_t*)zero_begin, 0u, zero_u32);
  count_deg_k<<<dim3((E + 255) / 256), b256, 0, stream>>>(dst, invdeg, E);
  inv_deg_k<<<dim3((N + 255) / 256), b256, 0, stream>>>(invdeg, N);
  lin0_k<<<dim3((N + 3) / 4), b256, 0, stream>>>(x, lin0_w, lin0_b, bufA, N);
  bounds_k<<<dim3((N + 255) / 256), b256, 0, stream>>>(batch, gstart, gend, N);
  edge_mlp1_pack_k<<<dim3((E + 63) / 64), dim3(128), 0, stream>>>(
      edge_attr, nn_w1, nn_b1, upk_hi, upk_lo, E);
  pack_w2_k<<<dim3(256), b256, 0, stream>>>(nn_w2, wpk_hi);

  float* cur = bufA;
  float* nxt = bufB;
  for (int it = 0; it < 3; ++it) {
    fused_msg_k<<<dim3((E + MSG_EDGES - 1) / MSG_EDGES), b256, 0, stream>>>(
        upk_hi, upk_lo, wpk_hi, cur, src, dst, invdeg, nn_b2, agg, E);
    convgru_k<<<dim3((N + 15) / 16), dim3(192), 0, stream>>>(
        agg, cur, conv_root, conv_bias, gru_wih, gru_whh, gru_bih, gru_bhh, nxt, N);
    float* tmp = cur; cur = nxt; nxt = tmp;
  }
  set2set_k<<<dim3(B), b256, 0, stream>>>(cur, gstart, gend,
      lstm_wih, lstm_whh, lstm_bih, lstm_bhh, lin1_w, lin1_b, lin2_w, lin2_b,
      enbuf, (float*)d_out);
}

// Round 12
// 801.516 us; speedup vs baseline: 2.3060x; 1.0444x over previous
//
#include <hip/hip_runtime.h>
#include <cstdint>
#include <cmath>

#define H 64
#define NFEAT 32
#define NNHID 128
#define MSG_EDGES 192   // 4 waves * 48 edges

typedef __attribute__((ext_vector_type(8))) short bf16x8;
typedef __attribute__((ext_vector_type(4))) float f32x4;

static __device__ __forceinline__ float sigmoidf_(float x) { return 1.f / (1.f + expf(-x)); }

static __device__ __forceinline__ unsigned bf16_rne_bits(float v) {
  unsigned u = __float_as_uint(v);
  return (u + 0x7fffu + ((u >> 16) & 1u)) >> 16;
}

// ---------------- generic fill ----------------
__global__ void fill_u32_k(uint32_t* __restrict__ p, uint32_t v, long long n) {
  long long i = (long long)blockIdx.x * blockDim.x + threadIdx.x;
  long long stride = (long long)gridDim.x * blockDim.x;
  for (; i < n; i += stride) p[i] = v;
}

// ---------------- degree ----------------
__global__ void count_deg_k(const int* __restrict__ dst, float* __restrict__ deg, int E) {
  int i = blockIdx.x * 256 + threadIdx.x;
  if (i < E) atomicAdd(&deg[dst[i]], 1.f);
}
__global__ void inv_deg_k(float* __restrict__ deg, int n) {
  int i = blockIdx.x * 256 + threadIdx.x;
  if (i < n) deg[i] = 1.f / fmaxf(deg[i], 1.f);
}

// ---------------- graph ranges via boundary detection (batch sorted) ----------------
__global__ void bounds_k(const int* __restrict__ batch, int* __restrict__ gs,
                         int* __restrict__ ge, int n) {
  int i = blockIdx.x * 256 + threadIdx.x;
  if (i >= n) return;
  int b = batch[i];
  if (i == 0) {
    gs[b] = 0;
  } else {
    int pb = batch[i - 1];
    if (pb != b) { gs[b] = i; ge[pb] = i; }
  }
  if (i == n - 1) ge[b] = n;
}

// ---------------- lin0 ----------------
__global__ __launch_bounds__(256) void lin0_k(const float* __restrict__ x,
    const float* __restrict__ w, const float* __restrict__ b,
    float* __restrict__ out, int n) {
  __shared__ float xr[4][NFEAT];
  int t = threadIdx.x;
  int nodeblk = blockIdx.x * 4;
  if (t < 4 * NFEAT) {
    int nn = nodeblk + t / NFEAT;
    xr[t / NFEAT][t % NFEAT] = (nn < n) ? x[(size_t)nn * NFEAT + (t % NFEAT)] : 0.f;
  }
  __syncthreads();
  int node = nodeblk + t / H;
  int c = t % H;
  if (node >= n) return;
  float acc = b[c];
  #pragma unroll
  for (int j = 0; j < NFEAT; ++j) acc += xr[t / H][j] * w[j * H + c];
  out[(size_t)node * H + c] = fmaxf(acc, 0.f);
}

// ------------- edge MLP layer1 + direct SINGLE-bf16 A-fragment pack -------------
__global__ __launch_bounds__(128) void edge_mlp1_pack_k(const float* __restrict__ ea,
    const float* __restrict__ w1, const float* __restrict__ b1,
    short* __restrict__ hi, int E) {
  __shared__ float ar[64][H];        // [edge][j]
  __shared__ float ut[NNHID][65];    // [k][e] padded
  int t = threadIdx.x;
  int e0 = blockIdx.x * 64;
  #pragma unroll
  for (int p = 0; p < 32; ++p) {
    int idx = p * 128 + t;
    int e = idx >> 6, j = idx & 63;
    ar[e][j] = (e0 + e < E) ? ea[(size_t)(e0 + e) * H + j] : 0.f;
  }
  __syncthreads();
  float bb = b1[t];
  for (int et = 0; et < 64; et += 16) {
    float acc[16];
    #pragma unroll
    for (int q = 0; q < 16; ++q) acc[q] = bb;
    #pragma unroll
    for (int j = 0; j < H; ++j) {
      float wv = w1[j * NNHID + t];
      #pragma unroll
      for (int q = 0; q < 16; ++q) acc[q] += ar[et + q][j] * wv;
    }
    #pragma unroll
    for (int q = 0; q < 16; ++q) ut[t][et + q] = fmaxf(acc[q], 0.f);
  }
  __syncthreads();
  // pack 16 local frags (4 etiles x 4 kt), 2 waves
  int wv = t >> 6, ln = t & 63;
  int erow = ln & 15;
  int k0b = (ln >> 4) * 8;
  for (int fi = wv; fi < 16; fi += 2) {
    int et = fi >> 2, kt = fi & 3;
    int k0 = kt * 32 + k0b;
    bool valid = (e0 + et * 16 + erow) < E;
    bf16x8 hv;
    #pragma unroll
    for (int b = 0; b < 8; ++b) {
      float v = valid ? ut[k0 + b][et * 16 + erow] : 0.f;
      hv[b] = (short)bf16_rne_bits(v);
    }
    size_t frag = ((size_t)(e0 >> 4) + et) * 4 + kt;
    size_t off = frag * 512 + ln * 8;
    *(bf16x8*)(hi + off) = hv;
  }
}

// ------- pack w2[128][4096] fp32 -> SINGLE bf16 B fragments (RNE) -------
__global__ __launch_bounds__(256) void pack_w2_k(const float* __restrict__ w2,
    short* __restrict__ hi) {
  int g = blockIdx.x * 256 + threadIdx.x;
  int lane = g & 63, frag = g >> 6;
  if (frag >= 1024) return;
  int ntile = frag >> 2, kt = frag & 3;
  int n = ntile * 16 + (lane & 15);
  int k0 = kt * 32 + (lane >> 4) * 8;
  bf16x8 hv;
  #pragma unroll
  for (int b = 0; b < 8; ++b) {
    float v = w2[(size_t)(k0 + b) * 4096 + n];
    hv[b] = (short)bf16_rne_bits(v);
  }
  size_t off = (size_t)frag * 512 + lane * 8;
  *(bf16x8*)(hi + off) = hv;
}

// ------- fused W-GEMM (bf16 x bf16 MFMA) + einsum + scatter-mean -------
// 4 waves/WG, 48 edges/wave (3 x 16-subtiles), 192 edges/WG.
__global__ __launch_bounds__(256, 2) void fused_msg_k(
    const short* __restrict__ upk_hi,
    const short* __restrict__ wpk_hi,
    const float* __restrict__ out, const int* __restrict__ src,
    const int* __restrict__ dst, const float* __restrict__ inv_deg,
    const float* __restrict__ b2, float* __restrict__ agg, int E) {
  __shared__ float s_lds[MSG_EDGES][H + 1];   // 49.9 KB
  int t = threadIdx.x;
  int e0 = blockIdx.x * MSG_EDGES;
  int wave = t >> 6, lane = t & 63;

  // stage s = out[src[e]]
  for (int rr = 0; rr < MSG_EDGES / 4; ++rr) {
    int row = wave + rr * 4;
    int e = e0 + row;
    int ee = e < E ? e : E - 1;
    int sn = src[ee];
    s_lds[row][lane] = out[(size_t)sn * H + lane];
  }
  __syncthreads();

  int lhi = lane >> 4;
  int lrow4 = lhi * 4;
  int lcol = lane & 15;
  int ebase = e0 + wave * 48;
  int srow = wave * 48;
  int etmax = (E - 1) >> 4;

  // A fragments: 3 subtiles x 4 ktiles (clamped etile; results discarded by e<E guard)
  bf16x8 a_hi[3][4];
  #pragma unroll
  for (int ms = 0; ms < 3; ++ms) {
    int et = (ebase >> 4) + ms;
    if (et > etmax) et = etmax;
    size_t base = (size_t)et * 4 * 512 + lane * 8;
    #pragma unroll
    for (int kt = 0; kt < 4; ++kt) {
      a_hi[ms][kt] = *(const bf16x8*)(upk_hi + base + (size_t)kt * 512);
    }
  }

  f32x4 msg[3][4];
  #pragma unroll
  for (int ms = 0; ms < 3; ++ms)
    #pragma unroll
    for (int oc = 0; oc < 4; ++oc) msg[ms][oc] = (f32x4){0.f, 0.f, 0.f, 0.f};

  const short* wh = wpk_hi + lane * 8;

  for (int i = 0; i < H; ++i) {
    float sv[3][4];
    #pragma unroll
    for (int ms = 0; ms < 3; ++ms)
      #pragma unroll
      for (int r = 0; r < 4; ++r)
        sv[ms][r] = s_lds[srow + ms * 16 + lrow4 + r][i];
    #pragma unroll
    for (int oc = 0; oc < 4; ++oc) {
      int ntile = i * 4 + oc;
      float b2v = b2[i * 64 + oc * 16 + lcol];
      bf16x8 bh[4];
      #pragma unroll
      for (int kt = 0; kt < 4; ++kt) {
        size_t off = (size_t)(ntile * 4 + kt) * 512;
        bh[kt] = *(const bf16x8*)(wh + off);
      }
      #pragma unroll
      for (int ms = 0; ms < 3; ++ms) {
        f32x4 acc = (f32x4){0.f, 0.f, 0.f, 0.f};
        #pragma unroll
        for (int kt = 0; kt < 4; ++kt) {
          acc = __builtin_amdgcn_mfma_f32_16x16x32_bf16(a_hi[ms][kt], bh[kt], acc, 0, 0, 0);
        }
        #pragma unroll
        for (int r = 0; r < 4; ++r)
          msg[ms][oc][r] += sv[ms][r] * (acc[r] + b2v);
      }
    }
  }

  // scatter-mean writeback
  #pragma unroll
  for (int ms = 0; ms < 3; ++ms) {
    #pragma unroll
    for (int r = 0; r < 4; ++r) {
      int e = ebase + ms * 16 + lrow4 + r;
      if (e < E) {
        int dn = dst[e];
        float idg = inv_deg[dn];
        #pragma unroll
        for (int oc = 0; oc < 4; ++oc) {
          atomicAdd(&agg[(size_t)dn * H + oc * 16 + lcol], msg[ms][oc][r] * idg);
        }
      }
    }
  }
}

// ------- fused conv + GRU (+ agg re-zero for next iteration) -------
__global__ __launch_bounds__(192) void convgru_k(float* __restrict__ agg,
    const float* __restrict__ h, const float* __restrict__ root,
    const float* __restrict__ cbias,
    const float* __restrict__ wih, const float* __restrict__ whh,
    const float* __restrict__ bih, const float* __restrict__ bhh,
    float* __restrict__ hnew, int n) {
  __shared__ float h_lds[16][H], m_lds[16][H];
  __shared__ float gib[16][192], ghb[16][192];
  int t = threadIdx.x;
  int n0 = blockIdx.x * 16;
  for (int p = 0; p < 6; ++p) {
    int idx = p * 192 + t;
    if (idx < 16 * H) {
      int q = idx >> 6, c = idx & 63;
      int nn = n0 + q;
      h_lds[q][c] = (nn < n) ? h[(size_t)nn * H + c] : 0.f;
    }
  }
  __syncthreads();
  for (int p = 0; p < 6; ++p) {
    int idx = p * 192 + t;
    if (idx < 16 * H) {
      int q = idx >> 6, c = idx & 63;
      int nn = n0 + q;
      float acc = cbias[c];
      if (nn < n) acc += agg[(size_t)nn * H + c];
      #pragma unroll
      for (int j = 0; j < H; ++j) acc += h_lds[q][j] * root[j * H + c];
      m_lds[q][c] = fmaxf(acc, 0.f);
      if (nn < n) agg[(size_t)nn * H + c] = 0.f;
    }
  }
  __syncthreads();
  float gi[16], gh[16];
  float bi = bih[t], bh = bhh[t];
  #pragma unroll
  for (int q = 0; q < 16; ++q) { gi[q] = bi; gh[q] = bh; }
  for (int j = 0; j < H; ++j) {
    float wi = wih[j * 192 + t];
    float wh = whh[j * 192 + t];
    #pragma unroll
    for (int q = 0; q < 16; ++q) {
      gi[q] += m_lds[q][j] * wi;
      gh[q] += h_lds[q][j] * wh;
    }
  }
  #pragma unroll
  for (int q = 0; q < 16; ++q) { gib[q][t] = gi[q]; ghb[q][t] = gh[q]; }
  __syncthreads();
  for (int p = 0; p < 6; ++p) {
    int idx = p * 192 + t;
    if (idx < 16 * H) {
      int q = idx >> 6, c = idx & 63;
      int nn = n0 + q;
      if (nn < n) {
        float r = sigmoidf_(gib[q][c] + ghb[q][c]);
        float z = sigmoidf_(gib[q][64 + c] + ghb[q][64 + c]);
        float ng = tanhf(gib[q][128 + c] + r * ghb[q][128 + c]);
        hnew[(size_t)nn * H + c] = (1.f - z) * ng + z * h_lds[q][c];
      }
    }
  }
}

// ------- fused Set2Set (3 steps of LSTM + attention) + final MLP -------
__global__ __launch_bounds__(256) void set2set_k(const float* __restrict__ out,
    const int* __restrict__ gstart, const int* __restrict__ gend,
    const float* __restrict__ wih, const float* __restrict__ whh,
    const float* __restrict__ bih, const float* __restrict__ bhh,
    const float* __restrict__ w1, const float* __restrict__ b1,
    const float* __restrict__ w2, const float* __restrict__ b2o,
    float* __restrict__ en, float* __restrict__ outp) {
  int b = blockIdx.x;
  int t = threadIdx.x;
  __shared__ float q_star[2 * H];
  __shared__ float hh[H], cc[H], q[H];
  __shared__ float gate[256];
  __shared__ float red[256];
  if (t < 2 * H) q_star[t] = 0.f;
  if (t >= 128 && t < 192) { hh[t - 128] = 0.f; cc[t - 128] = 0.f; }
  int s = gstart[b], epos = gend[b];
  if (s > epos) { s = 0; epos = 0; }
  __syncthreads();
  for (int step = 0; step < 3; ++step) {
    float acc = bih[t] + bhh[t];
    #pragma unroll 4
    for (int j = 0; j < 2 * H; ++j) acc += q_star[j] * wih[j * 256 + t];
    #pragma unroll 4
    for (int j = 0; j < H; ++j) acc += hh[j] * whh[j * 256 + t];
    gate[t] = acc;
    __syncthreads();
    if (t < H) {
      float ig = sigmoidf_(gate[t]);
      float fg = sigmoidf_(gate[64 + t]);
      float gg = tanhf(gate[128 + t]);
      float og = sigmoidf_(gate[192 + t]);
      float c2 = fg * cc[t] + ig * gg;
      cc[t] = c2;
      float h2 = og * tanhf(c2);
      hh[t] = h2;
      q[t] = h2;
    }
    __syncthreads();
    float lmax = -INFINITY;
    for (int nn = s + t; nn < epos; nn += 256) {
      float d = 0.f;
      const float* orow = &out[(size_t)nn * H];
      #pragma unroll
      for (int j = 0; j < H; ++j) d += orow[j] * q[j];
      en[nn] = d;
      lmax = fmaxf(lmax, d);
    }
    red[t] = lmax;
    __syncthreads();
    for (int st = 128; st > 0; st >>= 1) {
      if (t < st) red[t] = fmaxf(red[t], red[t + st]);
      __syncthreads();
    }
    float mx = red[0];
    __syncthreads();
    float lsum = 0.f;
    for (int nn = s + t; nn < epos; nn += 256) {
      float e_ = expf(en[nn] - mx);
      en[nn] = e_;
      lsum += e_;
    }
    red[t] = lsum;
    __syncthreads();
    for (int st = 128; st > 0; st >>= 1) {
      if (t < st) red[t] += red[t + st];
      __syncthreads();
    }
    float inv = 1.f / (red[0] + 1e-16f);
    __syncthreads();
    int hch = t & 63, sub = t >> 6;
    float racc = 0.f;
    for (int nn = s + sub; nn < epos; nn += 4) {
      racc += en[nn] * out[(size_t)nn * H + hch];
    }
    red[t] = racc;
    __syncthreads();
    if (t < H) {
      float r = (red[t] + red[64 + t] + red[128 + t] + red[192 + t]) * inv;
      q_star[t] = q[t];
      q_star[H + t] = r;
    }
    __syncthreads();
  }
  if (t < H) {
    float acc = b1[t];
    #pragma unroll 4
    for (int j = 0; j < 2 * H; ++j) acc += q_star[j] * w1[j * H + t];
    acc = fmaxf(acc, 0.f);
    red[t] = acc * w2[t];
  }
  __syncthreads();
  if (t < 64) {
    float v = red[t];
    #pragma unroll
    for (int off = 32; off > 0; off >>= 1) v += __shfl_down(v, off, 64);
    if (t == 0) outp[b] = v + b2o[0];
  }
}

extern "C" void kernel_launch(void* const* d_in, const int* in_sizes, int n_in,
                              void* d_out, int out_size, void* d_ws, size_t ws_size,
                              hipStream_t stream) {
  const float* x         = (const float*)d_in[0];
  const int*   edge_idx  = (const int*)d_in[1];
  const int*   batch     = (const int*)d_in[2];
  const float* edge_attr = (const float*)d_in[3];
  const float* lin0_w = (const float*)d_in[4];
  const float* lin0_b = (const float*)d_in[5];
  const float* nn_w1  = (const float*)d_in[6];
  const float* nn_b1  = (const float*)d_in[7];
  const float* nn_w2  = (const float*)d_in[8];
  const float* nn_b2  = (const float*)d_in[9];
  const float* conv_root = (const float*)d_in[10];
  const float* conv_bias = (const float*)d_in[11];
  const float* gru_wih = (const float*)d_in[12];
  const float* gru_whh = (const float*)d_in[13];
  const float* gru_bih = (const float*)d_in[14];
  const float* gru_bhh = (const float*)d_in[15];
  const float* lstm_wih = (const float*)d_in[16];
  const float* lstm_whh = (const float*)d_in[17];
  const float* lstm_bih = (const float*)d_in[18];
  const float* lstm_bhh = (const float*)d_in[19];
  const float* lin1_w = (const float*)d_in[20];
  const float* lin1_b = (const float*)d_in[21];
  const float* lin2_w = (const float*)d_in[22];
  const float* lin2_b = (const float*)d_in[23];

  int N = in_sizes[2];
  int E = in_sizes[1] / 2;
  int B = out_size;
  const int* src = edge_idx;
  const int* dst = edge_idx + E;

  char* p = (char*)d_ws;
  auto carve = [&](size_t bytes) -> void* {
    void* r = (void*)p;
    p += (bytes + 255) & ~(size_t)255;
    return r;
  };
  int etiles = (E + 15) / 16;
  int nfrag_u = etiles * 4;
  float* bufA   = (float*)carve((size_t)N * H * 4);
  float* bufB   = (float*)carve((size_t)N * H * 4);
  short* upk_hi = (short*)carve((size_t)nfrag_u * 512 * 2);
  short* wpk_hi = (short*)carve((size_t)1024 * 512 * 2);
  float* enbuf  = (float*)carve((size_t)N * 4);
  // --- contiguous zero region: invdeg, agg, gstart, gend ---
  char* zero_begin = p;
  float* invdeg = (float*)carve((size_t)N * 4);
  float* agg    = (float*)carve((size_t)N * H * 4);
  int*   gstart = (int*)carve((size_t)B * 4);
  int*   gend   = (int*)carve((size_t)B * 4);
  long long zero_u32 = (long long)(p - zero_begin) / 4;

  dim3 b256(256);
  fill_u32_k<<<dim3(1024), b256, 0, stream>>>((uint32_t*)zero_begin, 0u, zero_u32);
  count_deg_k<<<dim3((E + 255) / 256), b256, 0, stream>>>(dst, invdeg, E);
  inv_deg_k<<<dim3((N + 255) / 256), b256, 0, stream>>>(invdeg, N);
  lin0_k<<<dim3((N + 3) / 4), b256, 0, stream>>>(x, lin0_w, lin0_b, bufA, N);
  bounds_k<<<dim3((N + 255) / 256), b256, 0, stream>>>(batch, gstart, gend, N);
  edge_mlp1_pack_k<<<dim3((E + 63) / 64), dim3(128), 0, stream>>>(
      edge_attr, nn_w1, nn_b1, upk_hi, E);
  pack_w2_k<<<dim3(256), b256, 0, stream>>>(nn_w2, wpk_hi);

  float* cur = bufA;
  float* nxt = bufB;
  for (int it = 0; it < 3; ++it) {
    fused_msg_k<<<dim3((E + MSG_EDGES - 1) / MSG_EDGES), b256, 0, stream>>>(
        upk_hi, wpk_hi, cur, src, dst, invdeg, nn_b2, agg, E);
    convgru_k<<<dim3((N + 15) / 16), dim3(192), 0, stream>>>(
        agg, cur, conv_root, conv_bias, gru_wih, gru_whh, gru_bih, gru_bhh, nxt, N);
    float* tmp = cur; cur = nxt; nxt = tmp;
  }
  set2set_k<<<dim3(B), b256, 0, stream>>>(cur, gstart, gend,
      lstm_wih, lstm_whh, lstm_bih, lstm_bhh, lin1_w, lin1_b, lin2_w, lin2_b,
      enbuf, (float*)d_out);
}